// Round 10
// baseline (3478.096 us; speedup 1.0000x reference)
//
#include <hip/hip_runtime.h>
#include <math.h>

typedef float f32x4 __attribute__((ext_vector_type(4)));
typedef short s16x8 __attribute__((ext_vector_type(8)));
typedef unsigned short u16;

#define MFMA_BF16(a,b,c) __builtin_amdgcn_mfma_f32_16x16x32_bf16((a),(b),(c),0,0,0)
#define NBLK 243
#define PAIR_U16 13824   // one half-matrix tile: 27 kb * 512
#define SLOT_U16 27648   // c+h halves
#define LDS_BYTES 110592 // 2 slots * 27648 u16 * 2B
#define ST_SLOT 55296    // u16 per state slot (54 nt * 64 rows * 16 cols)

// Dataflow scan: 243 persistent blocks (1/CU), weights LDS-resident.
// State (bf16) [parity][slot][nt][64][16]: slots 0=s0 1=s1 2=s2 3=s3 4=s4 5=s5 6=s7 7=h
// Sync: per-wave epoch flags, one per 64B. CHUNKED gather: wait 14 tiles -> load
// 7 kb -> wait next 14 ... (overlaps straggler detect with LLC gather RTs).
// Scalar reads use single-flag waits. Polls: 3 hot iters then s_sleep(1).
// Loads = inline-asm global_load_dwordx4 sc1 bursts; stores = relaxed agent atomics.

struct P {
  const int* tokens; const void* masks; const int* pos; const int* ner;
  const void* hidden;
  const void* enc_W; const void* ner_W; const void* pos_W;
  const void* agg_W; const void* agg_b;
  const void* W0; const void* Ws;
  const void* dec_W; const void* dec_b;
  void* out;
  unsigned short* PK_agg; unsigned short* PK_rec; unsigned short* comb;
  unsigned short* xbf; unsigned short* Sbf;
  float* accr;
  int* ctrl; // [0]=bf16 flag; flags at 1024: F[g][mt][fi], one per 16 ints (64B)
};

#define FB(pp, g, mtv) ((pp).ctrl + 1024 + (((g) * 4 + (mtv)) * 54) * 16)

__device__ __forceinline__ unsigned short f2bf(float f) {
  union { float f; unsigned u; } v; v.f = f;
  return (unsigned short)((v.u + 0x7FFFu + ((v.u >> 16) & 1u)) >> 16);
}
__device__ __forceinline__ float bf2f(u16 x) {
  union { unsigned u; float f; } v; v.u = (unsigned)x << 16; return v.f;
}
__device__ __forceinline__ float ldf(const void* q, size_t i, int bf) {
  if (bf) return bf2f(((const u16*)q)[i]);
  return ((const float*)q)[i];
}
__device__ __forceinline__ void stout(void* o, size_t i, float v, int bf) {
  if (bf) ((u16*)o)[i] = f2bf(v);
  else    ((float*)o)[i] = v;
}
__device__ __forceinline__ float sigm(float x) { return 1.0f / (1.0f + expf(-x)); }
__device__ __forceinline__ float actf(int a, float x) {
  if (a == 0) return sigm(x);
  if (a == 1) return fmaxf(x, 0.0f);
  if (a == 2) return tanhf(x);
  return x;
}

// ---- LLC-coherent accessors ----
__device__ __forceinline__ s16x8 ldg16_sc1(const u16* p) {
  s16x8 r;
  asm volatile("global_load_dwordx4 %0, %1, off sc1" : "=v"(r) : "v"(p) : "memory");
  return r;
}
__device__ __forceinline__ void vmfence() {
  asm volatile("s_waitcnt vmcnt(0)" ::: "memory");
  __builtin_amdgcn_sched_barrier(0); // rule #18
}
__device__ __forceinline__ u16 ldc_u16(const u16* p) {
  return __hip_atomic_load(p, __ATOMIC_RELAXED, __HIP_MEMORY_SCOPE_AGENT);
}
__device__ __forceinline__ float ldc_f32(const float* p) {
  unsigned x = __hip_atomic_load((const unsigned*)p, __ATOMIC_RELAXED,
                                 __HIP_MEMORY_SCOPE_AGENT);
  union { unsigned u; float f; } v; v.u = x; return v.f;
}
__device__ __forceinline__ void stc_f32(float* p, float f) {
  union { float f; unsigned u; } v; v.f = f;
  __hip_atomic_store((unsigned*)p, v.u, __ATOMIC_RELAXED, __HIP_MEMORY_SCOPE_AGENT);
}
__device__ __forceinline__ void stc_u16(u16* p, u16 x) {
  __hip_atomic_store(p, x, __ATOMIC_RELAXED, __HIP_MEMORY_SCOPE_AGENT);
}
__device__ __forceinline__ void stc_i32(int* p, int x) {
  __hip_atomic_store(p, x, __ATOMIC_RELAXED, __HIP_MEMORY_SCOPE_AGENT);
}
__device__ __forceinline__ int ldc_i32(const int* p) {
  return __hip_atomic_load(p, __ATOMIC_RELAXED, __HIP_MEMORY_SCOPE_AGENT);
}

// ---- per-wave sync ----
__device__ __forceinline__ void setfW(int* fb, int fi, int e) {
  asm volatile("s_waitcnt vmcnt(0)" ::: "memory"); // drain this wave's state stores
  if ((threadIdx.x & 63) == 0) stc_i32(fb + fi * 16, e);
}
// wave polls flags [0,n) of a group (one flag per lane)
__device__ __forceinline__ void waitW(const int* fb, int n, int e) {
  int l = threadIdx.x & 63, it = 0;
  for (;;) {
    int ok = (l < n) ? (ldc_i32(fb + l * 16) >= e) : 1;
    if (__all(ok)) break;
    if (++it > 4000000) break; // bounded diagnostic escape
    if (it > 3) __builtin_amdgcn_s_sleep(1);
  }
  asm volatile("" ::: "memory");
}
// uniform single-flag wait (all lanes same address -> one broadcast request)
__device__ __forceinline__ void wait1(const int* f, int e) {
  int it = 0;
  while (ldc_i32(f) < e) {
    if (++it > 4000000) break;
    if (it > 3) __builtin_amdgcn_s_sleep(1);
  }
  asm volatile("" ::: "memory");
}

// ---------------- prep kernels ----------------

__global__ void k_detect(P p) {
  for (int j = threadIdx.x; j < 32768; j += 64) p.ctrl[j] = 0;
  __syncthreads();
  if (threadIdx.x == 0) {
    const u16* u = (const u16*)p.W0;
    int good = 0;
    for (int i = 0; i < 256; ++i) {
      int e = (u[i] >> 7) & 0xFF;
      if (e >= 90 && e <= 126) ++good;
    }
    p.ctrl[0] = (good >= 192) ? 1 : 0;
  }
}

__global__ __launch_bounds__(256) void k_init0(P p) { // zero Sbf + xbf pads
  const int total = 442368 + 114688;
  for (int e = blockIdx.x * blockDim.x + threadIdx.x; e < total;
       e += gridDim.x * blockDim.x) {
    if (e < 442368) {
      ((unsigned*)p.Sbf)[e] = 0u;
    } else {
      int e4 = e - 442368; int t = e4 / 896, r = e4 % 896;
      int b = r / 14, n = 850 + r % 14;
      p.xbf[((size_t)t * 64 + b) * 864 + n] = 0;
    }
  }
}

__global__ __launch_bounds__(256) void k_init1(P p) { // h(0) -> slot7 par0, tiled layout
  const int bf = p.ctrl[0];
  for (int e = blockIdx.x * blockDim.x + threadIdx.x; e < 54400;
       e += gridDim.x * blockDim.x) {
    int b = e / 850, n = e % 850;
    p.Sbf[(size_t)7 * ST_SLOT + (((size_t)(n >> 4) * 64 + b) << 4) + (n & 15)] =
        f2bf(ldf(p.hidden, e, bf));
  }
}

__global__ __launch_bounds__(256) void k_pack_agg(P p) {
  const int bf = p.ctrl[0];
  const long total = 801792L;
  for (long e = (long)blockIdx.x * blockDim.x + threadIdx.x; e < total;
       e += (long)gridDim.x * blockDim.x) {
    int j = (int)(e & 7), l = (int)((e >> 3) & 63);
    long q9 = e >> 9;
    int kb = (int)(q9 % 29), nt = (int)(q9 / 29);
    int n = nt * 16 + (l & 15);
    int k = kb * 32 + ((l >> 4) << 3) + j;
    float v = 0.0f;
    if (n < 850 && k < 910) v = ldf(p.agg_W, (size_t)n * 910 + k, bf);
    p.PK_agg[e] = f2bf(v);
  }
}

__global__ __launch_bounds__(256) void k_comb(P p) {
  const int bf = p.ctrl[0];
  const long total = 7602176L;
  for (long e = (long)blockIdx.x * blockDim.x + threadIdx.x; e < total;
       e += (long)gridDim.x * blockDim.x) {
    int k = (int)(e % 928);
    int r = (int)(e / 928);
    int t = r >> 6, b = r & 63;
    float v = 0.0f;
    if (k < 850)      { int tok = p.tokens[b * 128 + t]; v = ldf(p.enc_W, (size_t)tok * 850 + k, bf); }
    else if (k < 880) { int nv = p.ner[b * 128 + t];     v = ldf(p.ner_W, nv * 30 + (k - 850), bf); }
    else if (k < 910) { int pv = p.pos[b * 128 + t];     v = ldf(p.pos_W, pv * 30 + (k - 880), bf); }
    p.comb[e] = f2bf(v);
  }
}

__global__ __launch_bounds__(256) void k_pack_rec(P p) {
  const int bf = p.ctrl[0];
  const long total = 14929920L;
  for (long e = (long)blockIdx.x * blockDim.x + threadIdx.x; e < total;
       e += (long)gridDim.x * blockDim.x) {
    int j = (int)(e & 7), l = (int)((e >> 3) & 63);
    long q9 = e >> 9;
    int kb = (int)(q9 % 27);
    long q = q9 / 27;
    int nt = (int)(q % 54);
    int mh = (int)(q / 54);
    int half = mh & 1, mat = mh >> 1;
    int nl = nt * 16 + (l & 15);
    int col = half ? nl + 850 : nl;
    int k = kb * 32 + ((l >> 4) << 3) + j;
    float v = 0.0f;
    if (nl < 850 && k < 850) {
      if (mat == 0)      v = ldf(p.W0, (size_t)k * 1700 + col, bf);
      else if (mat == 1) v = ldf(p.W0, (size_t)(k + 850) * 1700 + col, bf);
      else               v = ldf(p.Ws, (size_t)(mat - 2) * 850 * 1700 + (size_t)k * 1700 + col, bf);
    }
    p.PK_rec[e] = f2bf(v);
  }
}

__global__ void k_diag(P p) {
  if (blockIdx.x == 0 && threadIdx.x == 0)
    for (int i = 0; i < 64; ++i) ((float*)p.out)[i] = 2000.0f;
}

__global__ __launch_bounds__(256) void k_phaseA(P p) {
  const int tid = threadIdx.x;
  const int l = tid & 63, lm = l & 15, lg = l >> 4;
  const int wid = (blockIdx.x << 2) | (tid >> 6);
  const int bf = p.ctrl[0];
  for (int u = wid; u < 512 * 54; u += 1024) {
    int mt = u / 54, nt = u - mt * 54;
    int r0 = mt << 4;
    f32x4 acc = {0.f, 0.f, 0.f, 0.f};
    const u16* Arow = p.comb + (size_t)(r0 + lm) * 928 + (size_t)lg * 8;
    const u16* Bp = p.PK_agg + (size_t)nt * 29 * 512 + (size_t)l * 8;
    for (int kb = 0; kb < 29; ++kb) {
      s16x8 a = *(const s16x8*)(Arow + (size_t)kb * 32);
      s16x8 b = *(const s16x8*)(Bp + (size_t)kb * 512);
      acc = MFMA_BF16(a, b, acc);
    }
    int n = nt * 16 + lm;
    if (n < 850) {
      float bias = ldf(p.agg_b, n, bf);
#pragma unroll
      for (int i = 0; i < 4; ++i) {
        int r = r0 + lg * 4 + i;
        p.xbf[(size_t)r * 864 + n] = f2bf(acc[i] + bias);
      }
    }
  }
}

// ---------------- scan units (chunked flag-gather overlap) ----------------
// Chunk c covers tiles [0,14/28/42/54) and kb [0,7/14/21/27).

// A+prev from state slot; chunked wait on producer flags fb at epoch e.
__device__ __forceinline__ void unitSC(const u16* lds, const u16* st, const int* fb,
                                       int e, int nt, int mt, int l,
                                       f32x4& cc, f32x4& hh, float* prev) {
  const int lm = l & 15, lg = l >> 4;
  const int row = mt * 16 + lm;
  const u16* A = st + (((size_t)(lg >> 1) * 64 + row) << 4) + ((lg & 1) << 3);
  s16x8 ab[27];
  waitW(fb, 14, e);
#pragma unroll
  for (int kb = 0; kb < 7; ++kb) ab[kb] = ldg16_sc1(A + (size_t)kb * 2048);
  waitW(fb, 28, e);
#pragma unroll
  for (int kb = 7; kb < 14; ++kb) ab[kb] = ldg16_sc1(A + (size_t)kb * 2048);
  waitW(fb, 42, e);
#pragma unroll
  for (int kb = 14; kb < 21; ++kb) ab[kb] = ldg16_sc1(A + (size_t)kb * 2048);
  waitW(fb, 54, e);
#pragma unroll
  for (int kb = 21; kb < 27; ++kb) ab[kb] = ldg16_sc1(A + (size_t)kb * 2048);
  u16 pv[4];
#pragma unroll
  for (int i = 0; i < 4; ++i)
    pv[i] = ldc_u16(st + (((size_t)nt * 64 + mt * 16 + lg * 4 + i) << 4) + lm);
  vmfence();
  const f32x4 z = {0.f, 0.f, 0.f, 0.f};
  f32x4 c0 = z, c1 = z, h0 = z, h1 = z;
#pragma unroll
  for (int kb = 0; kb < 27; ++kb) {
    s16x8 bc = *(const s16x8*)(lds + l * 8 + (size_t)kb * 512);
    s16x8 bh = *(const s16x8*)(lds + PAIR_U16 + l * 8 + (size_t)kb * 512);
    if (kb & 1) { c1 = MFMA_BF16(ab[kb], bc, c1); h1 = MFMA_BF16(ab[kb], bh, h1); }
    else        { c0 = MFMA_BF16(ab[kb], bc, c0); h0 = MFMA_BF16(ab[kb], bh, h0); }
  }
  cc += c0 + c1; hh += h0 + h1;
#pragma unroll
  for (int i = 0; i < 4; ++i) prev[i] = bf2f(pv[i]);
}

// One shared A burst (chunked wait), two LDS B slots; prev at tiles ntA, ntB.
__device__ __forceinline__ void unit2SC(const u16* lds0, const u16* lds1, const u16* st,
                                        const int* fb, int e, int ntA, int ntB,
                                        int mt, int l,
                                        f32x4& cA, f32x4& hA, f32x4& cB, f32x4& hB,
                                        float* prevA, float* prevB) {
  const int lm = l & 15, lg = l >> 4;
  const int row = mt * 16 + lm;
  const u16* A = st + (((size_t)(lg >> 1) * 64 + row) << 4) + ((lg & 1) << 3);
  s16x8 ab[27];
  waitW(fb, 14, e);
#pragma unroll
  for (int kb = 0; kb < 7; ++kb) ab[kb] = ldg16_sc1(A + (size_t)kb * 2048);
  waitW(fb, 28, e);
#pragma unroll
  for (int kb = 7; kb < 14; ++kb) ab[kb] = ldg16_sc1(A + (size_t)kb * 2048);
  waitW(fb, 42, e);
#pragma unroll
  for (int kb = 14; kb < 21; ++kb) ab[kb] = ldg16_sc1(A + (size_t)kb * 2048);
  waitW(fb, 54, e);
#pragma unroll
  for (int kb = 21; kb < 27; ++kb) ab[kb] = ldg16_sc1(A + (size_t)kb * 2048);
  u16 pa[4], pb[4];
#pragma unroll
  for (int i = 0; i < 4; ++i) {
    size_t r2 = mt * 16 + lg * 4 + i;
    pa[i] = ldc_u16(st + (((size_t)ntA * 64 + r2) << 4) + lm);
    pb[i] = ldc_u16(st + (((size_t)ntB * 64 + r2) << 4) + lm);
  }
  vmfence();
#pragma unroll
  for (int kb = 0; kb < 27; ++kb) {
    cA = MFMA_BF16(ab[kb], *(const s16x8*)(lds0 + l * 8 + (size_t)kb * 512), cA);
    hA = MFMA_BF16(ab[kb], *(const s16x8*)(lds0 + PAIR_U16 + l * 8 + (size_t)kb * 512), hA);
    cB = MFMA_BF16(ab[kb], *(const s16x8*)(lds1 + l * 8 + (size_t)kb * 512), cB);
    hB = MFMA_BF16(ab[kb], *(const s16x8*)(lds1 + PAIR_U16 + l * 8 + (size_t)kb * 512), hB);
  }
#pragma unroll
  for (int i = 0; i < 4; ++i) { prevA[i] = bf2f(pa[i]); prevB[i] = bf2f(pb[i]); }
}

// x-part of L0: plain loads (L2-hot), B = W0_lo c/h from global PK_rec.
__device__ __forceinline__ void unit_x(const P& p, int nt, int t, int mt, int l,
                                       f32x4& cc, f32x4& hh) {
  const int lm = l & 15, lg = l >> 4;
  const u16* Ax = p.xbf + ((size_t)t * 64 + mt * 16 + lm) * 864 + (size_t)lg * 8;
  const u16* B0 = p.PK_rec + (size_t)(0 * 54 + nt) * PAIR_U16 + l * 8;
  const u16* B1 = p.PK_rec + (size_t)(1 * 54 + nt) * PAIR_U16 + l * 8;
  s16x8 ab[27];
#pragma unroll
  for (int kb = 0; kb < 27; ++kb) ab[kb] = *(const s16x8*)(Ax + (size_t)kb * 32);
  const f32x4 z = {0.f, 0.f, 0.f, 0.f};
  f32x4 c0 = z, c1 = z, h0 = z, h1 = z;
#pragma unroll
  for (int kb = 0; kb < 27; ++kb) {
    s16x8 bc = *(const s16x8*)(B0 + (size_t)kb * 512);
    s16x8 bh = *(const s16x8*)(B1 + (size_t)kb * 512);
    if (kb & 1) { c1 = MFMA_BF16(ab[kb], bc, c1); h1 = MFMA_BF16(ab[kb], bh, h1); }
    else        { c0 = MFMA_BF16(ab[kb], bc, c0); h0 = MFMA_BF16(ab[kb], bh, h0); }
  }
  cc += c0 + c1; hh += h0 + h1;
}

__device__ __forceinline__ void epiS(const P& p, int par, int slot, int nt, int mt,
                                     int l, const float* prev, int act,
                                     f32x4 c, f32x4 h) {
  int lm = l & 15, lg = l >> 4, n = nt * 16 + lm;
  if (n >= 850) return;
  u16* dst = p.Sbf + (size_t)(par * 8 + slot) * ST_SLOT;
#pragma unroll
  for (int i = 0; i < 4; ++i) {
    size_t row = mt * 16 + lg * 4 + i;
    float s = prev[i] + sigm(c[i]) * (actf(act, h[i]) - prev[i]);
    stc_u16(dst + (((size_t)nt * 64 + row) << 4) + lm, f2bf(s));
  }
}

__global__ __launch_bounds__(256, 1) void k_scan(P p) {
  extern __shared__ u16 ldsw[];
  const int tid = threadIdx.x;
  const int l = tid & 63, lm = l & 15, lg = l >> 4, mt = tid >> 6;
  const int blk = blockIdx.x;
  const int bf = p.ctrl[0];
#define STP(par, slot) (p.Sbf + (size_t)((par) * 8 + (slot)) * ST_SLOT)

  int role, matA, ntA, matB, ntB;
  if (blk < 54)       { role = 0; matA = 1; ntA = blk;       matB = 3; ntB = ntA; }
  else if (blk < 108) { role = 1; matA = 2; ntA = blk - 54;  matB = 4; ntB = ntA; }
  else if (blk < 162) { role = 2; matA = 6; ntA = blk - 108; matB = 5; ntB = ntA; }
  else if (blk < 216) { role = 3; matA = 7; ntA = blk - 162; matB = 9; ntB = ntA; }
  else                { role = 4; matA = 8; ntA = 2 * (blk - 216); matB = 8; ntB = ntA + 1; }

  for (int s = 0; s < 2; ++s) {
    int m = s ? matB : matA, nt = s ? ntB : ntA;
    for (int h = 0; h < 2; ++h) {
      const uint4* src = (const uint4*)(p.PK_rec + ((size_t)(m * 2 + h) * 54 + nt) * PAIR_U16);
      uint4* dst = (uint4*)(ldsw + s * SLOT_U16 + h * PAIR_U16);
      for (int i = tid; i < PAIR_U16 / 8; i += 256) dst[i] = src[i];
    }
  }
  __syncthreads();

  const f32x4 z = {0.f, 0.f, 0.f, 0.f};

  if (role == 0) {
    const int fi = blk;
    for (int t = 0; t < 128; ++t) {
      int par = t & 1;
      f32x4 cc = z, hh = z;
      unit_x(p, ntA, t, mt, l, cc, hh);      // x@W0_lo, overlaps the F4 chunk waits
      float pv[4];
      unitSC(ldsw, STP(par, 7), FB(p, 7, mt), t, ntA, mt, l, cc, hh, pv); // + h@W0_hi
      epiS(p, par, 0, ntA, mt, l, pv, 2, cc, hh);        // s0 (tanh)
      setfW(FB(p, 0, mt), fi, t + 1);
      f32x4 c2 = z, h2 = z; float p2[4];
      unitSC(ldsw + SLOT_U16, STP(par, 1), FB(p, 1, mt), t + 1, ntA, mt, l, c2, h2, p2);
      epiS(p, par, 2, ntA, mt, l, p2, 1, c2, h2);        // s2 (relu)
      setfW(FB(p, 2, mt), fi, t + 1);
    }
    // decoder + log_softmax: blocks 0..15, one wave per batch row
    if (blk < 16) {
      int b = blk * 4 + mt;
      waitW(FB(p, 7, b >> 4), 54, 128);
      float myval = 0.0f;
      for (int c = 0; c < 42; ++c) {
        float part = 0.0f;
        for (int d = l; d < 850; d += 64)
          part += ldc_f32(p.accr + b * 850 + d) * ldf(p.dec_W, c * 850 + d, bf);
        for (int off = 32; off > 0; off >>= 1) part += __shfl_xor(part, off);
        if (l == c) myval = part * (1.0f / 128.0f) + ldf(p.dec_b, c, bf);
      }
      float mx = (l < 42) ? myval : -INFINITY;
      for (int off = 32; off > 0; off >>= 1) mx = fmaxf(mx, __shfl_xor(mx, off));
      float ex = (l < 42) ? expf(myval - mx) : 0.0f;
      float sm = ex;
      for (int off = 32; off > 0; off >>= 1) sm += __shfl_xor(sm, off);
      if (l < 42) stout(p.out, (size_t)b * 42 + l, myval - mx - logf(sm), bf);
    }
  } else if (role == 1) {
    const int fi = blk - 54;
    for (int t = 0; t < 128; ++t) {
      int par = t & 1;
      f32x4 cc = z, hh = z; float pv[4];
      unitSC(ldsw, STP(par, 0), FB(p, 0, mt), t + 1, ntA, mt, l, cc, hh, pv); // s0@Ws[0]
      epiS(p, par, 1, ntA, mt, l, pv, 0, cc, hh);        // s1 (sigmoid)
      setfW(FB(p, 1, mt), fi, t + 1);
      f32x4 c2 = z, h2 = z; float p2[4];
      unitSC(ldsw + SLOT_U16, STP(par, 1), FB(p, 1, mt), t + 1, ntA, mt, l, c2, h2, p2);
      epiS(p, par, 3, ntA, mt, l, p2, 1, c2, h2);        // s3 (relu)
      setfW(FB(p, 3, mt), fi, t + 1);
    }
  } else if (role == 2) {
    const int fi = blk - 108;
    for (int t = 0; t < 128; ++t) {
      int par = t & 1;
      f32x4 cc = z, hh = z; float pv[4];
      unitSC(ldsw + SLOT_U16, STP(par, 1), FB(p, 1, mt), t + 1, ntA, mt, l, cc, hh, pv);
      epiS(p, par, 4, ntA, mt, l, pv, 3, cc, hh);        // s4 (identity)
      setfW(FB(p, 4, mt), fi, t + 1);
      f32x4 c2 = z, h2 = z; float p2[4];
      unitSC(ldsw, STP(par, 2), FB(p, 2, mt), t + 1, ntA, mt, l, c2, h2, p2); // s2@Ws[4]
      epiS(p, par, 5, ntA, mt, l, p2, 2, c2, h2);        // s5 (tanh)
      setfW(FB(p, 5, mt), fi, t + 1);
    }
  } else if (role == 4) {
    const int fi = blk - 216;
    for (int t = 0; t < 128; ++t) {
      int par = t & 1;
      f32x4 cA = z, hA = z, cB = z, hB = z; float pa[4], pb[4];
      unit2SC(ldsw, ldsw + SLOT_U16, STP(par, 3), FB(p, 3, mt), t + 1,
              ntA, ntB, mt, l, cA, hA, cB, hB, pa, pb);  // s3@Ws[6], 2 nt
      epiS(p, par, 6, ntA, mt, l, pa, 2, cA, hA);        // s7 (tanh)
      epiS(p, par, 6, ntB, mt, l, pb, 2, cB, hB);
      setfW(FB(p, 6, mt), fi, t + 1);
    }
  } else { // role 3
    const int fi = blk - 162;
    float areg[4] = {0.f, 0.f, 0.f, 0.f};
    const int n = ntA * 16 + lm;
    for (int t = 0; t < 128; ++t) {
      int par = t & 1, par2 = (t + 1) & 1;
      // psum needs only tile ntA of s1..s4 -> three single-flag waits
      wait1(FB(p, 2, mt) + ntA * 16, t + 1);
      wait1(FB(p, 3, mt) + ntA * 16, t + 1);
      wait1(FB(p, 4, mt) + ntA * 16, t + 1);
      float psum[4];
      {
        u16 q1[4], q2[4], q3[4], q4[4];
#pragma unroll
        for (int i = 0; i < 4; ++i) {
          size_t off = (((size_t)ntA * 64 + mt * 16 + lg * 4 + i) << 4) + lm;
          q1[i] = ldc_u16(STP(par, 1) + off); q2[i] = ldc_u16(STP(par, 2) + off);
          q3[i] = ldc_u16(STP(par, 3) + off); q4[i] = ldc_u16(STP(par, 4) + off);
        }
#pragma unroll
        for (int i = 0; i < 4; ++i)
          psum[i] = bf2f(q1[i]) + bf2f(q2[i]) + bf2f(q3[i]) + bf2f(q4[i]);
      }
      f32x4 cA = z, hA = z, cB = z, hB = z; float s5v[4], s5d[4];
      unit2SC(ldsw, ldsw + SLOT_U16, STP(par, 5), FB(p, 5, mt), t + 1,
              ntA, ntA, mt, l, cA, hA, cB, hB, s5v, s5d); // s5@Ws[5], s5@Ws[7]
      wait1(FB(p, 6, mt) + (ntA >> 1) * 16, t + 1);       // s7 tile ntA only
      u16 q7[4];
#pragma unroll
      for (int i = 0; i < 4; ++i)
        q7[i] = ldc_u16(STP(par, 6) + (((size_t)ntA * 64 + mt * 16 + lg * 4 + i) << 4) + lm);
      if (n < 850) {
        u16* hdst = STP(par2, 7);
#pragma unroll
        for (int i = 0; i < 4; ++i) {
          int b = mt * 16 + lg * 4 + i;
          float s6 = s5v[i] + sigm(cA[i]) * (sigm(hA[i]) - s5v[i]);
          float s8 = s5v[i] + sigm(cB[i]) * (fmaxf(hB[i], 0.f) - s5v[i]);
          float sum = psum[i] + s5v[i] + bf2f(q7[i]) + s6 + s8;
          float outv = sum * 0.125f;
          float mk = ldf(p.masks, b * 128 + t, bf);
          areg[i] += outv * mk;
          stc_u16(hdst + (((size_t)ntA * 64 + b) << 4) + lm, f2bf(outv));
          if (t == 127) {
            stout(p.out, 2688 + (size_t)b * 850 + n, outv * mk, bf);
            stc_f32(p.accr + b * 850 + n, areg[i]);
          }
        }
      }
      setfW(FB(p, 7, mt), fi, t + 1);
    }
  }
#undef STP
}

// ---------------- launch ----------------

extern "C" void kernel_launch(void* const* d_in, const int* in_sizes, int n_in,
                              void* d_out, int out_size, void* d_ws, size_t ws_size,
                              hipStream_t stream) {
  (void)in_sizes; (void)n_in; (void)out_size;
  P p;
  p.tokens = (const int*)d_in[0];
  p.masks  = d_in[1];
  p.pos    = (const int*)d_in[2];
  p.ner    = (const int*)d_in[3];
  p.hidden = d_in[4];
  p.enc_W  = d_in[5];
  p.ner_W  = d_in[6];
  p.pos_W  = d_in[7];
  p.agg_W  = d_in[8];
  p.agg_b  = d_in[9];
  p.W0     = d_in[10];
  p.Ws     = d_in[11];
  p.dec_W  = d_in[12];
  p.dec_b  = d_in[13];
  p.out    = d_out;

  unsigned char* ws = (unsigned char*)d_ws;
  p.ctrl = (int*)ws;
  unsigned char* R0 = ws + 262144; // ctrl region: 1024 + 8*4*54*16 ints < 256KB
  p.PK_agg = (unsigned short*)R0;
  p.comb   = (unsigned short*)(R0 + 1603584);
  p.PK_rec = (unsigned short*)R0;
  unsigned char* q = R0 + 29859840;
  p.xbf  = (unsigned short*)q; q += 14155776;
  p.Sbf  = (unsigned short*)q; q += 1769472;
  p.accr = (float*)q;          q += 217600;

  size_t need = (size_t)(q - ws);
  if (ws_size < need) {
    hipLaunchKernelGGL(k_diag, dim3(1), dim3(64), 0, stream, p);
    return;
  }

  static int lds_attr_set = 0;
  if (!lds_attr_set) { // host-side attribute, idempotent, graph-capture safe
    (void)hipFuncSetAttribute((const void*)k_scan,
                              hipFuncAttributeMaxDynamicSharedMemorySize, LDS_BYTES);
    lds_attr_set = 1;
  }

  hipLaunchKernelGGL(k_detect,   dim3(1),    dim3(64),  0, stream, p);
  hipLaunchKernelGGL(k_init0,    dim3(256),  dim3(256), 0, stream, p);
  hipLaunchKernelGGL(k_init1,    dim3(64),   dim3(256), 0, stream, p);
  hipLaunchKernelGGL(k_pack_agg, dim3(512),  dim3(256), 0, stream, p);
  hipLaunchKernelGGL(k_comb,     dim3(4096), dim3(256), 0, stream, p);
  hipLaunchKernelGGL(k_phaseA,   dim3(256),  dim3(256), 0, stream, p);
  hipLaunchKernelGGL(k_pack_rec, dim3(4096), dim3(256), 0, stream, p);
  hipLaunchKernelGGL(k_scan,     dim3(NBLK), dim3(256), LDS_BYTES, stream, p);
}

// Round 12
// 3098.898 us; speedup vs baseline: 1.1224x; 1.1224x over previous
//
#include <hip/hip_runtime.h>
#include <math.h>

typedef float f32x4 __attribute__((ext_vector_type(4)));
typedef short s16x8 __attribute__((ext_vector_type(8)));
typedef unsigned short u16;

#define MFMA_BF16(a,b,c) __builtin_amdgcn_mfma_f32_16x16x32_bf16((a),(b),(c),0,0,0)
#define NBLK 243
#define PAIR_U16 13824   // one half-matrix tile: 27 kb * 512
#define SLOT_U16 27648   // c+h halves
#define LDS_BYTES 110592 // 2 slots * 27648 u16 * 2B
#define ST_SLOT 55296    // u16 per state slot (54 nt * 64 rows * 16 cols)

// Dataflow scan: 243 persistent blocks (1/CU), weights LDS-resident.
// State (bf16) [parity][slot][nt][64][16]: slots 0=s0 1=s1 2=s2 3=s3 4=s4 5=s5 6=s7 7=h
// Sync: per-wave epoch flags, one per 64B. LATCHED polls (satisfied lanes stop
// issuing loads) + progress-adaptive backoff (sleep 2 -> 16 when no progress):
// collapses idle-wave poll bandwidth at the LLC.
// Loads = inline-asm global_load_dwordx4 sc1 bursts; stores = relaxed agent atomics.

struct P {
  const int* tokens; const void* masks; const int* pos; const int* ner;
  const void* hidden;
  const void* enc_W; const void* ner_W; const void* pos_W;
  const void* agg_W; const void* agg_b;
  const void* W0; const void* Ws;
  const void* dec_W; const void* dec_b;
  void* out;
  unsigned short* PK_agg; unsigned short* PK_rec; unsigned short* comb;
  unsigned short* xbf; unsigned short* Sbf;
  float* accr;
  int* ctrl; // [0]=bf16 flag; flags at 1024: F[g][mt][fi], one per 16 ints (64B)
};

#define FB(pp, g, mtv) ((pp).ctrl + 1024 + (((g) * 4 + (mtv)) * 54) * 16)

__device__ __forceinline__ unsigned short f2bf(float f) {
  union { float f; unsigned u; } v; v.f = f;
  return (unsigned short)((v.u + 0x7FFFu + ((v.u >> 16) & 1u)) >> 16);
}
__device__ __forceinline__ float bf2f(u16 x) {
  union { unsigned u; float f; } v; v.u = (unsigned)x << 16; return v.f;
}
__device__ __forceinline__ float ldf(const void* q, size_t i, int bf) {
  if (bf) return bf2f(((const u16*)q)[i]);
  return ((const float*)q)[i];
}
__device__ __forceinline__ void stout(void* o, size_t i, float v, int bf) {
  if (bf) ((u16*)o)[i] = f2bf(v);
  else    ((float*)o)[i] = v;
}
__device__ __forceinline__ float sigm(float x) { return 1.0f / (1.0f + expf(-x)); }
__device__ __forceinline__ float actf(int a, float x) {
  if (a == 0) return sigm(x);
  if (a == 1) return fmaxf(x, 0.0f);
  if (a == 2) return tanhf(x);
  return x;
}

// ---- LLC-coherent accessors ----
__device__ __forceinline__ s16x8 ldg16_sc1(const u16* p) {
  s16x8 r;
  asm volatile("global_load_dwordx4 %0, %1, off sc1" : "=v"(r) : "v"(p) : "memory");
  return r;
}
__device__ __forceinline__ void vmfence() {
  asm volatile("s_waitcnt vmcnt(0)" ::: "memory");
  __builtin_amdgcn_sched_barrier(0); // rule #18
}
__device__ __forceinline__ u16 ldc_u16(const u16* p) {
  return __hip_atomic_load(p, __ATOMIC_RELAXED, __HIP_MEMORY_SCOPE_AGENT);
}
__device__ __forceinline__ float ldc_f32(const float* p) {
  unsigned x = __hip_atomic_load((const unsigned*)p, __ATOMIC_RELAXED,
                                 __HIP_MEMORY_SCOPE_AGENT);
  union { unsigned u; float f; } v; v.u = x; return v.f;
}
__device__ __forceinline__ void stc_f32(float* p, float f) {
  union { float f; unsigned u; } v; v.f = f;
  __hip_atomic_store((unsigned*)p, v.u, __ATOMIC_RELAXED, __HIP_MEMORY_SCOPE_AGENT);
}
__device__ __forceinline__ void stc_u16(u16* p, u16 x) {
  __hip_atomic_store(p, x, __ATOMIC_RELAXED, __HIP_MEMORY_SCOPE_AGENT);
}
__device__ __forceinline__ void stc_i32(int* p, int x) {
  __hip_atomic_store(p, x, __ATOMIC_RELAXED, __HIP_MEMORY_SCOPE_AGENT);
}
__device__ __forceinline__ int ldc_i32(const int* p) {
  return __hip_atomic_load(p, __ATOMIC_RELAXED, __HIP_MEMORY_SCOPE_AGENT);
}

// backoff helper: constant-arg s_sleep (builtin requires literal)
__device__ __forceinline__ void backoff(int it) {
  if (it > 12)     __builtin_amdgcn_s_sleep(16);
  else if (it > 2) __builtin_amdgcn_s_sleep(2);
}

// ---- per-wave sync ----
__device__ __forceinline__ void setfW(int* fb, int fi, int e) {
  asm volatile("s_waitcnt vmcnt(0)" ::: "memory"); // drain this wave's state stores
  if ((threadIdx.x & 63) == 0) stc_i32(fb + fi * 16, e);
}
// Latched adaptive poll: satisfied lanes stop issuing loads; backoff escalates
// when no progress, resets to fast mode on any progress.
__device__ __forceinline__ void waitL(const int* fb, int n, int e) {
  int l = threadIdx.x & 63;
  bool done = (l >= n);
  int it = 0, last = -1, guard = 0;
  for (;;) {
    if (!done) done = (ldc_i32(fb + l * 16) >= e);
    unsigned long long m = __ballot(done);
    if (m == ~0ULL) break;
    int cnt = (int)__popcll(m);
    if (cnt != last) { last = cnt; it = 0; }
    if (++guard > 8000000) break; // bounded diagnostic escape
    ++it;
    backoff(it);
  }
  asm volatile("" ::: "memory");
}
// uniform single-flag wait (all lanes same address -> one line per poll)
__device__ __forceinline__ void wait1(const int* f, int e) {
  int it = 0, guard = 0;
  while (ldc_i32(f) < e) {
    if (++guard > 8000000) break;
    ++it;
    backoff(it);
  }
  asm volatile("" ::: "memory");
}

// ---------------- prep kernels ----------------

__global__ void k_detect(P p) {
  for (int j = threadIdx.x; j < 32768; j += 64) p.ctrl[j] = 0;
  __syncthreads();
  if (threadIdx.x == 0) {
    const u16* u = (const u16*)p.W0;
    int good = 0;
    for (int i = 0; i < 256; ++i) {
      int e = (u[i] >> 7) & 0xFF;
      if (e >= 90 && e <= 126) ++good;
    }
    p.ctrl[0] = (good >= 192) ? 1 : 0;
  }
}

__global__ __launch_bounds__(256) void k_init0(P p) { // zero Sbf + xbf pads
  const int total = 442368 + 114688;
  for (int e = blockIdx.x * blockDim.x + threadIdx.x; e < total;
       e += gridDim.x * blockDim.x) {
    if (e < 442368) {
      ((unsigned*)p.Sbf)[e] = 0u;
    } else {
      int e4 = e - 442368; int t = e4 / 896, r = e4 % 896;
      int b = r / 14, n = 850 + r % 14;
      p.xbf[((size_t)t * 64 + b) * 864 + n] = 0;
    }
  }
}

__global__ __launch_bounds__(256) void k_init1(P p) { // h(0) -> slot7 par0, tiled layout
  const int bf = p.ctrl[0];
  for (int e = blockIdx.x * blockDim.x + threadIdx.x; e < 54400;
       e += gridDim.x * blockDim.x) {
    int b = e / 850, n = e % 850;
    p.Sbf[(size_t)7 * ST_SLOT + (((size_t)(n >> 4) * 64 + b) << 4) + (n & 15)] =
        f2bf(ldf(p.hidden, e, bf));
  }
}

__global__ __launch_bounds__(256) void k_pack_agg(P p) {
  const int bf = p.ctrl[0];
  const long total = 801792L;
  for (long e = (long)blockIdx.x * blockDim.x + threadIdx.x; e < total;
       e += (long)gridDim.x * blockDim.x) {
    int j = (int)(e & 7), l = (int)((e >> 3) & 63);
    long q9 = e >> 9;
    int kb = (int)(q9 % 29), nt = (int)(q9 / 29);
    int n = nt * 16 + (l & 15);
    int k = kb * 32 + ((l >> 4) << 3) + j;
    float v = 0.0f;
    if (n < 850 && k < 910) v = ldf(p.agg_W, (size_t)n * 910 + k, bf);
    p.PK_agg[e] = f2bf(v);
  }
}

__global__ __launch_bounds__(256) void k_comb(P p) {
  const int bf = p.ctrl[0];
  const long total = 7602176L;
  for (long e = (long)blockIdx.x * blockDim.x + threadIdx.x; e < total;
       e += (long)gridDim.x * blockDim.x) {
    int k = (int)(e % 928);
    int r = (int)(e / 928);
    int t = r >> 6, b = r & 63;
    float v = 0.0f;
    if (k < 850)      { int tok = p.tokens[b * 128 + t]; v = ldf(p.enc_W, (size_t)tok * 850 + k, bf); }
    else if (k < 880) { int nv = p.ner[b * 128 + t];     v = ldf(p.ner_W, nv * 30 + (k - 850), bf); }
    else if (k < 910) { int pv = p.pos[b * 128 + t];     v = ldf(p.pos_W, pv * 30 + (k - 880), bf); }
    p.comb[e] = f2bf(v);
  }
}

__global__ __launch_bounds__(256) void k_pack_rec(P p) {
  const int bf = p.ctrl[0];
  const long total = 14929920L;
  for (long e = (long)blockIdx.x * blockDim.x + threadIdx.x; e < total;
       e += (long)gridDim.x * blockDim.x) {
    int j = (int)(e & 7), l = (int)((e >> 3) & 63);
    long q9 = e >> 9;
    int kb = (int)(q9 % 27);
    long q = q9 / 27;
    int nt = (int)(q % 54);
    int mh = (int)(q / 54);
    int half = mh & 1, mat = mh >> 1;
    int nl = nt * 16 + (l & 15);
    int col = half ? nl + 850 : nl;
    int k = kb * 32 + ((l >> 4) << 3) + j;
    float v = 0.0f;
    if (nl < 850 && k < 850) {
      if (mat == 0)      v = ldf(p.W0, (size_t)k * 1700 + col, bf);
      else if (mat == 1) v = ldf(p.W0, (size_t)(k + 850) * 1700 + col, bf);
      else               v = ldf(p.Ws, (size_t)(mat - 2) * 850 * 1700 + (size_t)k * 1700 + col, bf);
    }
    p.PK_rec[e] = f2bf(v);
  }
}

__global__ void k_diag(P p) {
  if (blockIdx.x == 0 && threadIdx.x == 0)
    for (int i = 0; i < 64; ++i) ((float*)p.out)[i] = 2000.0f;
}

__global__ __launch_bounds__(256) void k_phaseA(P p) {
  const int tid = threadIdx.x;
  const int l = tid & 63, lm = l & 15, lg = l >> 4;
  const int wid = (blockIdx.x << 2) | (tid >> 6);
  const int bf = p.ctrl[0];
  for (int u = wid; u < 512 * 54; u += 1024) {
    int mt = u / 54, nt = u - mt * 54;
    int r0 = mt << 4;
    f32x4 acc = {0.f, 0.f, 0.f, 0.f};
    const u16* Arow = p.comb + (size_t)(r0 + lm) * 928 + (size_t)lg * 8;
    const u16* Bp = p.PK_agg + (size_t)nt * 29 * 512 + (size_t)l * 8;
    for (int kb = 0; kb < 29; ++kb) {
      s16x8 a = *(const s16x8*)(Arow + (size_t)kb * 32);
      s16x8 b = *(const s16x8*)(Bp + (size_t)kb * 512);
      acc = MFMA_BF16(a, b, acc);
    }
    int n = nt * 16 + lm;
    if (n < 850) {
      float bias = ldf(p.agg_b, n, bf);
#pragma unroll
      for (int i = 0; i < 4; ++i) {
        int r = r0 + lg * 4 + i;
        p.xbf[(size_t)r * 864 + n] = f2bf(acc[i] + bias);
      }
    }
  }
}

// ---------------- scan units ----------------

// A burst from tiled state slot: fragment (row, k..k+7) at ((2kb+(lg>>1))*64+row)*16+(lg&1)*8
__device__ __forceinline__ void burstA(const u16* st, int mt, int l, s16x8* ab) {
  const int lm = l & 15, lg = l >> 4;
  const int row = mt * 16 + lm;
  const u16* A = st + (((size_t)(lg >> 1) * 64 + row) << 4) + ((lg & 1) << 3);
#pragma unroll
  for (int kb = 0; kb < 27; ++kb) ab[kb] = ldg16_sc1(A + (size_t)kb * 2048);
}

__device__ __forceinline__ void unitS(const u16* lds, const u16* st, int nt, int mt,
                                      int l, f32x4& cc, f32x4& hh, float* prev) {
  const int lm = l & 15, lg = l >> 4;
  s16x8 ab[27];
  burstA(st, mt, l, ab);
  u16 pv[4];
#pragma unroll
  for (int i = 0; i < 4; ++i)
    pv[i] = ldc_u16(st + (((size_t)nt * 64 + mt * 16 + lg * 4 + i) << 4) + lm);
  vmfence();
  const f32x4 z = {0.f, 0.f, 0.f, 0.f};
  f32x4 c0 = z, c1 = z, h0 = z, h1 = z;
#pragma unroll
  for (int kb = 0; kb < 27; ++kb) {
    s16x8 bc = *(const s16x8*)(lds + l * 8 + (size_t)kb * 512);
    s16x8 bh = *(const s16x8*)(lds + PAIR_U16 + l * 8 + (size_t)kb * 512);
    if (kb & 1) { c1 = MFMA_BF16(ab[kb], bc, c1); h1 = MFMA_BF16(ab[kb], bh, h1); }
    else        { c0 = MFMA_BF16(ab[kb], bc, c0); h0 = MFMA_BF16(ab[kb], bh, h0); }
  }
  cc += c0 + c1; hh += h0 + h1;
#pragma unroll
  for (int i = 0; i < 4; ++i) prev[i] = bf2f(pv[i]);
}

__device__ __forceinline__ void unit2S(const u16* lds0, const u16* lds1, const u16* st,
                                       int ntA, int ntB, int mt, int l,
                                       f32x4& cA, f32x4& hA, f32x4& cB, f32x4& hB,
                                       float* prevA, float* prevB) {
  const int lm = l & 15, lg = l >> 4;
  s16x8 ab[27];
  burstA(st, mt, l, ab);
  u16 pa[4], pb[4];
#pragma unroll
  for (int i = 0; i < 4; ++i) {
    size_t row = mt * 16 + lg * 4 + i;
    pa[i] = ldc_u16(st + (((size_t)ntA * 64 + row) << 4) + lm);
    pb[i] = ldc_u16(st + (((size_t)ntB * 64 + row) << 4) + lm);
  }
  vmfence();
#pragma unroll
  for (int kb = 0; kb < 27; ++kb) {
    cA = MFMA_BF16(ab[kb], *(const s16x8*)(lds0 + l * 8 + (size_t)kb * 512), cA);
    hA = MFMA_BF16(ab[kb], *(const s16x8*)(lds0 + PAIR_U16 + l * 8 + (size_t)kb * 512), hA);
    cB = MFMA_BF16(ab[kb], *(const s16x8*)(lds1 + l * 8 + (size_t)kb * 512), cB);
    hB = MFMA_BF16(ab[kb], *(const s16x8*)(lds1 + PAIR_U16 + l * 8 + (size_t)kb * 512), hB);
  }
#pragma unroll
  for (int i = 0; i < 4; ++i) { prevA[i] = bf2f(pa[i]); prevB[i] = bf2f(pb[i]); }
}

__device__ __forceinline__ void unit_x(const P& p, int nt, int t, int mt, int l,
                                       f32x4& cc, f32x4& hh) {
  const int lm = l & 15, lg = l >> 4;
  const u16* Ax = p.xbf + ((size_t)t * 64 + mt * 16 + lm) * 864 + (size_t)lg * 8;
  const u16* B0 = p.PK_rec + (size_t)(0 * 54 + nt) * PAIR_U16 + l * 8;
  const u16* B1 = p.PK_rec + (size_t)(1 * 54 + nt) * PAIR_U16 + l * 8;
  s16x8 ab[27];
#pragma unroll
  for (int kb = 0; kb < 27; ++kb) ab[kb] = *(const s16x8*)(Ax + (size_t)kb * 32);
  const f32x4 z = {0.f, 0.f, 0.f, 0.f};
  f32x4 c0 = z, c1 = z, h0 = z, h1 = z;
#pragma unroll
  for (int kb = 0; kb < 27; ++kb) {
    s16x8 bc = *(const s16x8*)(B0 + (size_t)kb * 512);
    s16x8 bh = *(const s16x8*)(B1 + (size_t)kb * 512);
    if (kb & 1) { c1 = MFMA_BF16(ab[kb], bc, c1); h1 = MFMA_BF16(ab[kb], bh, h1); }
    else        { c0 = MFMA_BF16(ab[kb], bc, c0); h0 = MFMA_BF16(ab[kb], bh, h0); }
  }
  cc += c0 + c1; hh += h0 + h1;
}

__device__ __forceinline__ void epiS(const P& p, int par, int slot, int nt, int mt,
                                     int l, const float* prev, int act,
                                     f32x4 c, f32x4 h) {
  int lm = l & 15, lg = l >> 4, n = nt * 16 + lm;
  if (n >= 850) return;
  u16* dst = p.Sbf + (size_t)(par * 8 + slot) * ST_SLOT;
#pragma unroll
  for (int i = 0; i < 4; ++i) {
    size_t row = mt * 16 + lg * 4 + i;
    float s = prev[i] + sigm(c[i]) * (actf(act, h[i]) - prev[i]);
    stc_u16(dst + (((size_t)nt * 64 + row) << 4) + lm, f2bf(s));
  }
}

__global__ __launch_bounds__(256, 1) void k_scan(P p) {
  extern __shared__ u16 ldsw[];
  const int tid = threadIdx.x;
  const int l = tid & 63, lm = l & 15, lg = l >> 4, mt = tid >> 6;
  const int blk = blockIdx.x;
  const int bf = p.ctrl[0];
#define STP(par, slot) (p.Sbf + (size_t)((par) * 8 + (slot)) * ST_SLOT)

  int role, matA, ntA, matB, ntB;
  if (blk < 54)       { role = 0; matA = 1; ntA = blk;       matB = 3; ntB = ntA; }
  else if (blk < 108) { role = 1; matA = 2; ntA = blk - 54;  matB = 4; ntB = ntA; }
  else if (blk < 162) { role = 2; matA = 6; ntA = blk - 108; matB = 5; ntB = ntA; }
  else if (blk < 216) { role = 3; matA = 7; ntA = blk - 162; matB = 9; ntB = ntA; }
  else                { role = 4; matA = 8; ntA = 2 * (blk - 216); matB = 8; ntB = ntA + 1; }

  for (int s = 0; s < 2; ++s) {
    int m = s ? matB : matA, nt = s ? ntB : ntA;
    for (int h = 0; h < 2; ++h) {
      const uint4* src = (const uint4*)(p.PK_rec + ((size_t)(m * 2 + h) * 54 + nt) * PAIR_U16);
      uint4* dst = (uint4*)(ldsw + s * SLOT_U16 + h * PAIR_U16);
      for (int i = tid; i < PAIR_U16 / 8; i += 256) dst[i] = src[i];
    }
  }
  __syncthreads();

  const f32x4 z = {0.f, 0.f, 0.f, 0.f};

  if (role == 0) {
    const int fi = blk;
    for (int t = 0; t < 128; ++t) {
      int par = t & 1;
      f32x4 cc = z, hh = z;
      unit_x(p, ntA, t, mt, l, cc, hh);      // x@W0_lo, overlaps the F4 wait
      waitL(FB(p, 7, mt), 54, t);             // h(t) ready (this m-tile)
      float pv[4];
      unitS(ldsw, STP(par, 7), ntA, mt, l, cc, hh, pv);  // + h@W0_hi
      epiS(p, par, 0, ntA, mt, l, pv, 2, cc, hh);        // s0 (tanh)
      setfW(FB(p, 0, mt), fi, t + 1);
      waitL(FB(p, 1, mt), 54, t + 1);
      f32x4 c2 = z, h2 = z; float p2[4];
      unitS(ldsw + SLOT_U16, STP(par, 1), ntA, mt, l, c2, h2, p2); // s1@Ws[1]
      epiS(p, par, 2, ntA, mt, l, p2, 1, c2, h2);        // s2 (relu)
      setfW(FB(p, 2, mt), fi, t + 1);
    }
    // decoder + log_softmax: blocks 0..15, one wave per batch row
    if (blk < 16) {
      int b = blk * 4 + mt;
      waitL(FB(p, 7, b >> 4), 54, 128);
      float myval = 0.0f;
      for (int c = 0; c < 42; ++c) {
        float part = 0.0f;
        for (int d = l; d < 850; d += 64)
          part += ldc_f32(p.accr + b * 850 + d) * ldf(p.dec_W, c * 850 + d, bf);
        for (int off = 32; off > 0; off >>= 1) part += __shfl_xor(part, off);
        if (l == c) myval = part * (1.0f / 128.0f) + ldf(p.dec_b, c, bf);
      }
      float mx = (l < 42) ? myval : -INFINITY;
      for (int off = 32; off > 0; off >>= 1) mx = fmaxf(mx, __shfl_xor(mx, off));
      float ex = (l < 42) ? expf(myval - mx) : 0.0f;
      float sm = ex;
      for (int off = 32; off > 0; off >>= 1) sm += __shfl_xor(sm, off);
      if (l < 42) stout(p.out, (size_t)b * 42 + l, myval - mx - logf(sm), bf);
    }
  } else if (role == 1) {
    const int fi = blk - 54;
    for (int t = 0; t < 128; ++t) {
      int par = t & 1;
      waitL(FB(p, 0, mt), 54, t + 1);
      f32x4 cc = z, hh = z; float pv[4];
      unitS(ldsw, STP(par, 0), ntA, mt, l, cc, hh, pv);  // s0@Ws[0]
      epiS(p, par, 1, ntA, mt, l, pv, 0, cc, hh);        // s1 (sigmoid)
      setfW(FB(p, 1, mt), fi, t + 1);
      waitL(FB(p, 1, mt), 54, t + 1);                    // all s1 tiles
      f32x4 c2 = z, h2 = z; float p2[4];
      unitS(ldsw + SLOT_U16, STP(par, 1), ntA, mt, l, c2, h2, p2); // s1@Ws[2]
      epiS(p, par, 3, ntA, mt, l, p2, 1, c2, h2);        // s3 (relu)
      setfW(FB(p, 3, mt), fi, t + 1);
    }
  } else if (role == 2) {
    const int fi = blk - 108;
    for (int t = 0; t < 128; ++t) {
      int par = t & 1;
      waitL(FB(p, 1, mt), 54, t + 1);
      f32x4 cc = z, hh = z; float pv[4];
      unitS(ldsw + SLOT_U16, STP(par, 1), ntA, mt, l, cc, hh, pv); // s1@Ws[3]
      epiS(p, par, 4, ntA, mt, l, pv, 3, cc, hh);        // s4 (identity)
      setfW(FB(p, 4, mt), fi, t + 1);
      waitL(FB(p, 2, mt), 54, t + 1);
      f32x4 c2 = z, h2 = z; float p2[4];
      unitS(ldsw, STP(par, 2), ntA, mt, l, c2, h2, p2);  // s2@Ws[4]
      epiS(p, par, 5, ntA, mt, l, p2, 2, c2, h2);        // s5 (tanh)
      setfW(FB(p, 5, mt), fi, t + 1);
    }
  } else if (role == 4) {
    const int fi = blk - 216;
    for (int t = 0; t < 128; ++t) {
      int par = t & 1;
      waitL(FB(p, 3, mt), 54, t + 1);
      f32x4 cA = z, hA = z, cB = z, hB = z; float pa[4], pb[4];
      unit2S(ldsw, ldsw + SLOT_U16, STP(par, 3), ntA, ntB, mt, l,
             cA, hA, cB, hB, pa, pb);                    // s3@Ws[6], 2 nt
      epiS(p, par, 6, ntA, mt, l, pa, 2, cA, hA);        // s7 (tanh)
      epiS(p, par, 6, ntB, mt, l, pb, 2, cB, hB);
      setfW(FB(p, 6, mt), fi, t + 1);
    }
  } else { // role 3
    const int fi = blk - 162;
    float areg[4] = {0.f, 0.f, 0.f, 0.f};
    const int n = ntA * 16 + lm;
    for (int t = 0; t < 128; ++t) {
      int par = t & 1, par2 = (t + 1) & 1;
      // psum needs only tile ntA of s1..s4 -> three single-flag waits
      wait1(FB(p, 2, mt) + ntA * 16, t + 1);
      wait1(FB(p, 3, mt) + ntA * 16, t + 1);
      wait1(FB(p, 4, mt) + ntA * 16, t + 1);
      float psum[4];
      {
        u16 q1[4], q2[4], q3[4], q4[4];
#pragma unroll
        for (int i = 0; i < 4; ++i) {
          size_t off = (((size_t)ntA * 64 + mt * 16 + lg * 4 + i) << 4) + lm;
          q1[i] = ldc_u16(STP(par, 1) + off); q2[i] = ldc_u16(STP(par, 2) + off);
          q3[i] = ldc_u16(STP(par, 3) + off); q4[i] = ldc_u16(STP(par, 4) + off);
        }
#pragma unroll
        for (int i = 0; i < 4; ++i)
          psum[i] = bf2f(q1[i]) + bf2f(q2[i]) + bf2f(q3[i]) + bf2f(q4[i]);
      }
      waitL(FB(p, 5, mt), 54, t + 1);
      f32x4 cA = z, hA = z, cB = z, hB = z; float s5v[4], s5d[4];
      unit2S(ldsw, ldsw + SLOT_U16, STP(par, 5), ntA, ntA, mt, l,
             cA, hA, cB, hB, s5v, s5d);                  // s5@Ws[5], s5@Ws[7]
      wait1(FB(p, 6, mt) + (ntA >> 1) * 16, t + 1);      // s7 tile ntA only
      u16 q7[4];
#pragma unroll
      for (int i = 0; i < 4; ++i)
        q7[i] = ldc_u16(STP(par, 6) + (((size_t)ntA * 64 + mt * 16 + lg * 4 + i) << 4) + lm);
      if (n < 850) {
        u16* hdst = STP(par2, 7);
#pragma unroll
        for (int i = 0; i < 4; ++i) {
          int b = mt * 16 + lg * 4 + i;
          float s6 = s5v[i] + sigm(cA[i]) * (sigm(hA[i]) - s5v[i]);
          float s8 = s5v[i] + sigm(cB[i]) * (fmaxf(hB[i], 0.f) - s5v[i]);
          float sum = psum[i] + s5v[i] + bf2f(q7[i]) + s6 + s8;
          float outv = sum * 0.125f;
          float mk = ldf(p.masks, b * 128 + t, bf);
          areg[i] += outv * mk;
          stc_u16(hdst + (((size_t)ntA * 64 + b) << 4) + lm, f2bf(outv));
          if (t == 127) {
            stout(p.out, 2688 + (size_t)b * 850 + n, outv * mk, bf);
            stc_f32(p.accr + b * 850 + n, areg[i]);
          }
        }
      }
      setfW(FB(p, 7, mt), fi, t + 1);
    }
  }
#undef STP
}

// ---------------- launch ----------------

extern "C" void kernel_launch(void* const* d_in, const int* in_sizes, int n_in,
                              void* d_out, int out_size, void* d_ws, size_t ws_size,
                              hipStream_t stream) {
  (void)in_sizes; (void)n_in; (void)out_size;
  P p;
  p.tokens = (const int*)d_in[0];
  p.masks  = d_in[1];
  p.pos    = (const int*)d_in[2];
  p.ner    = (const int*)d_in[3];
  p.hidden = d_in[4];
  p.enc_W  = d_in[5];
  p.ner_W  = d_in[6];
  p.pos_W  = d_in[7];
  p.agg_W  = d_in[8];
  p.agg_b  = d_in[9];
  p.W0     = d_in[10];
  p.Ws     = d_in[11];
  p.dec_W  = d_in[12];
  p.dec_b  = d_in[13];
  p.out    = d_out;

  unsigned char* ws = (unsigned char*)d_ws;
  p.ctrl = (int*)ws;
  unsigned char* R0 = ws + 262144; // ctrl region: 1024 + 8*4*54*16 ints < 256KB
  p.PK_agg = (unsigned short*)R0;
  p.comb   = (unsigned short*)(R0 + 1603584);
  p.PK_rec = (unsigned short*)R0;
  unsigned char* q = R0 + 29859840;
  p.xbf  = (unsigned short*)q; q += 14155776;
  p.Sbf  = (unsigned short*)q; q += 1769472;
  p.accr = (float*)q;          q += 217600;

  size_t need = (size_t)(q - ws);
  if (ws_size < need) {
    hipLaunchKernelGGL(k_diag, dim3(1), dim3(64), 0, stream, p);
    return;
  }

  static int lds_attr_set = 0;
  if (!lds_attr_set) { // host-side attribute, idempotent, graph-capture safe
    (void)hipFuncSetAttribute((const void*)k_scan,
                              hipFuncAttributeMaxDynamicSharedMemorySize, LDS_BYTES);
    lds_attr_set = 1;
  }

  hipLaunchKernelGGL(k_detect,   dim3(1),    dim3(64),  0, stream, p);
  hipLaunchKernelGGL(k_init0,    dim3(256),  dim3(256), 0, stream, p);
  hipLaunchKernelGGL(k_init1,    dim3(64),   dim3(256), 0, stream, p);
  hipLaunchKernelGGL(k_pack_agg, dim3(512),  dim3(256), 0, stream, p);
  hipLaunchKernelGGL(k_comb,     dim3(4096), dim3(256), 0, stream, p);
  hipLaunchKernelGGL(k_phaseA,   dim3(256),  dim3(256), 0, stream, p);
  hipLaunchKernelGGL(k_pack_rec, dim3(4096), dim3(256), 0, stream, p);
  hipLaunchKernelGGL(k_scan,     dim3(NBLK), dim3(256), LDS_BYTES, stream, p);
}